// Round 1
// baseline (402.236 us; speedup 1.0000x reference)
//
#include <hip/hip_runtime.h>
#include <math.h>

#define B_ 32
#define P_ 8732
#define C_ 81
#define K_ 16
#define THRESH 0.5f

// ---------------- init ----------------
__global__ void init_ws(unsigned long long* best_key, int* n_pos, double* sums) {
    int t = threadIdx.x;
    if (t < B_ * K_) best_key[t] = 0ULL;
    if (t < B_) n_pos[t] = 0;
    if (t < 3) sums[t] = 0.0;
}

// ---------------- match: per-prior max/argmax over K, per-object argmax over P ----------------
__global__ __launch_bounds__(256) void match_kernel(
    const float* __restrict__ boxes,   // [B,K,4] xyxy
    const float* __restrict__ priors,  // [P,4] cxcywh
    float* __restrict__ prior_max,     // [B,P]
    int* __restrict__ obj_for_prior,   // [B,P]
    unsigned long long* __restrict__ best_key) // [B,K]
{
    __shared__ float bx1[K_], by1[K_], bx2[K_], by2[K_], barea[K_];
    const int b = blockIdx.y;
    const int tid = threadIdx.x;
    if (tid < K_) {
        float x1 = boxes[(b * K_ + tid) * 4 + 0];
        float y1 = boxes[(b * K_ + tid) * 4 + 1];
        float x2 = boxes[(b * K_ + tid) * 4 + 2];
        float y2 = boxes[(b * K_ + tid) * 4 + 3];
        bx1[tid] = x1; by1[tid] = y1; bx2[tid] = x2; by2[tid] = y2;
        barea[tid] = (x2 - x1) * (y2 - y1);
    }
    __syncthreads();

    const int p = blockIdx.x * 256 + tid;
    const bool valid = (p < P_);
    float px1 = 0, py1 = 0, px2 = 0, py2 = 0, parea = 0;
    if (valid) {
        float4 pc = *(const float4*)(priors + (size_t)p * 4);
        px1 = pc.x - pc.z * 0.5f; py1 = pc.y - pc.w * 0.5f;
        px2 = pc.x + pc.z * 0.5f; py2 = pc.y + pc.w * 0.5f;
        parea = (px2 - px1) * (py2 - py1);   // match ref: area from xyxy coords
    }

    float best = -1.0f; int barg = 0;
    unsigned long long keys[K_];
#pragma unroll
    for (int k = 0; k < K_; ++k) {
        unsigned long long key = 0ULL;
        float ov = -1.0f;
        if (valid) {
            float ltx = fmaxf(bx1[k], px1), lty = fmaxf(by1[k], py1);
            float rbx = fminf(bx2[k], px2), rby = fminf(by2[k], py2);
            float w = fmaxf(rbx - ltx, 0.0f), h = fmaxf(rby - lty, 0.0f);
            float inter = w * h;
            ov = inter / (barea[k] + parea - inter);
            unsigned int bits = __float_as_uint(ov); // ov >= 0 -> monotone as uint
            key = ((unsigned long long)bits << 32) |
                  (unsigned long long)(0xFFFFFFFFu - (unsigned int)p); // smallest p wins ties
        }
        if (ov > best) { best = ov; barg = k; }  // strict > : first-index tie-break
        keys[k] = key;
    }
    if (valid) {
        prior_max[(size_t)b * P_ + p] = best;
        obj_for_prior[(size_t)b * P_ + p] = barg;
    }
    // wave-reduce each object's key, one global atomic per wave
#pragma unroll
    for (int k = 0; k < K_; ++k) {
        unsigned long long key = keys[k];
        for (int off = 32; off > 0; off >>= 1) {
            unsigned long long o = __shfl_down(key, off, 64);
            if (o > key) key = o;
        }
        if ((tid & 63) == 0) atomicMax(&best_key[b * K_ + k], key);
    }
}

// ---------------- override: each object claims its best prior (serial, last-k wins) ----------------
__global__ void override_kernel(float* __restrict__ prior_max,
                                int* __restrict__ obj_for_prior,
                                const unsigned long long* __restrict__ best_key) {
    int b = blockIdx.x;
    if (threadIdx.x == 0) {
        for (int k = 0; k < K_; ++k) {
            unsigned long long key = best_key[b * K_ + k];
            unsigned int p = 0xFFFFFFFFu - (unsigned int)(key & 0xFFFFFFFFu);
            obj_for_prior[(size_t)b * P_ + p] = k;
            prior_max[(size_t)b * P_ + p] = THRESH + 0.1f;
        }
    }
}

// ---------------- CE + box L1 + ce_neg store ----------------
__global__ __launch_bounds__(256) void ce_kernel(
    const float* __restrict__ locs,    // [B,P,4]
    const float* __restrict__ scores,  // [B,P,C]
    const float* __restrict__ boxes,   // [B,K,4]
    const int* __restrict__ labels,    // [B,K]
    const float* __restrict__ priors,  // [P,4]
    const float* __restrict__ prior_max,
    const int* __restrict__ obj_for_prior,
    float* __restrict__ ce_neg,
    int* __restrict__ n_pos,
    double* __restrict__ sums)         // [0]=pos_ce [1]=hard [2]=l1
{
    const int b = blockIdx.y;
    const int p = blockIdx.x * 256 + threadIdx.x;
    if (p >= P_) return;
    const size_t bp = (size_t)b * P_ + p;

    const int obj = obj_for_prior[bp];
    const float pm = prior_max[bp];
    const bool pos = (pm >= THRESH);            // labels always >= 1
    const int lbl = pos ? labels[b * K_ + obj] : 0;

    const float* s = scores + bp * C_;
    float m = -INFINITY, acc = 0.0f, sl = 0.0f;
#pragma unroll 3
    for (int c = 0; c < C_; ++c) {
        float x = s[c];
        if (c == lbl) sl = x;
        if (x > m) { acc = acc * __expf(m - x) + 1.0f; m = x; }
        else       { acc += __expf(x - m); }
    }
    const float ce = (m + logf(acc)) - sl;

    ce_neg[bp] = pos ? 0.0f : ce;

    if (pos) {
        atomicAdd(&n_pos[b], 1);
        atomicAdd(&sums[0], (double)ce);
        // encode(xy_to_cxcy(box), prior) and L1 vs predicted locs
        float4 bb = *(const float4*)(boxes + ((size_t)b * K_ + obj) * 4);
        float4 pc = *(const float4*)(priors + (size_t)p * 4);
        float cx = (bb.x + bb.z) * 0.5f, cy = (bb.y + bb.w) * 0.5f;
        float w = bb.z - bb.x, h = bb.w - bb.y;
        float gx = (cx - pc.x) / (pc.z / 10.0f);
        float gy = (cy - pc.y) / (pc.w / 10.0f);
        float gw = logf(w / pc.z) * 5.0f;
        float gh = logf(h / pc.w) * 5.0f;
        float4 pl = *(const float4*)(locs + bp * 4);
        float l1 = fabsf(pl.x - gx) + fabsf(pl.y - gy) + fabsf(pl.z - gw) + fabsf(pl.w - gh);
        atomicAdd(&sums[2], (double)l1);
    }
}

// ---------------- per-image top-M sum via bit-level binary search ----------------
__global__ __launch_bounds__(256) void topm_kernel(
    const float* __restrict__ ce_neg,
    const int* __restrict__ n_pos,
    double* __restrict__ sums)
{
    const int b = blockIdx.x;
    const int tid = threadIdx.x;
    const int NV = (P_ + 255) / 256;  // 35
    __shared__ int s_cnt[4];
    __shared__ double s_sum[4];

    float v[NV];
    const float* src = ce_neg + (size_t)b * P_;
#pragma unroll
    for (int j = 0; j < NV; ++j) {
        int idx = tid + j * 256;
        v[j] = (idx < P_) ? src[idx] : -1.0f;  // sentinel loses all >=0 compares
    }
    const int M = 3 * n_pos[b];

    double S_partial = 0.0;
    int c_partial = 0;
    float tval = 0.0f;
    bool sum_all = (M >= P_);

    if (!sum_all) {
        unsigned int lo = 0u, hi = 0x7f800000u;
        while (hi - lo > 1u) {
            unsigned int mid = (lo + hi) >> 1;
            float t = __uint_as_float(mid);
            int c = 0;
#pragma unroll
            for (int j = 0; j < NV; ++j) c += (v[j] >= t) ? 1 : 0;
            for (int off = 32; off > 0; off >>= 1) c += __shfl_down(c, off, 64);
            if ((tid & 63) == 0) s_cnt[tid >> 6] = c;
            __syncthreads();
            int tot = s_cnt[0] + s_cnt[1] + s_cnt[2] + s_cnt[3];
            __syncthreads();
            if (tot >= M) lo = mid; else hi = mid;
        }
        tval = __uint_as_float(lo);
#pragma unroll
        for (int j = 0; j < NV; ++j) {
            if (v[j] > tval) { c_partial++; S_partial += (double)v[j]; }
        }
    } else {
#pragma unroll
        for (int j = 0; j < NV; ++j) {
            if (v[j] >= 0.0f) S_partial += (double)v[j];
        }
    }

    for (int off = 32; off > 0; off >>= 1) {
        S_partial += __shfl_down(S_partial, off, 64);
        c_partial += __shfl_down(c_partial, off, 64);
    }
    if ((tid & 63) == 0) { s_cnt[tid >> 6] = c_partial; s_sum[tid >> 6] = S_partial; }
    __syncthreads();
    if (tid == 0) {
        int ctot = s_cnt[0] + s_cnt[1] + s_cnt[2] + s_cnt[3];
        double stot = s_sum[0] + s_sum[1] + s_sum[2] + s_sum[3];
        if (!sum_all) stot += (double)(M - ctot) * (double)tval;
        atomicAdd(&sums[1], stot);
    }
}

// ---------------- final combine ----------------
__global__ void final_kernel(const int* __restrict__ n_pos,
                             const double* __restrict__ sums,
                             float* __restrict__ out) {
    if (threadIdx.x == 0) {
        int tot = 0;
        for (int b = 0; b < B_; ++b) tot += n_pos[b];
        float n = (float)tot;
        double class_loss = (sums[0] + sums[1]) / (double)n;
        double box_loss = sums[2] / ((double)n * 4.0);
        out[0] = (float)(class_loss + box_loss);
    }
}

extern "C" void kernel_launch(void* const* d_in, const int* in_sizes, int n_in,
                              void* d_out, int out_size, void* d_ws, size_t ws_size,
                              hipStream_t stream) {
    const float* locs   = (const float*)d_in[0];
    const float* scores = (const float*)d_in[1];
    const float* boxes  = (const float*)d_in[2];
    const int*   labels = (const int*)d_in[3];
    const float* priors = (const float*)d_in[4];
    float* out = (float*)d_out;

    char* ws = (char*)d_ws;
    unsigned long long* best_key = (unsigned long long*)ws;          // 512*8 = 4096 B
    int*    n_pos      = (int*)(ws + 4096);                          // 128 B
    double* sums       = (double*)(ws + 4352);                       // 24 B
    float*  prior_max  = (float*)(ws + 4608);                        // B*P*4
    int*    obj_for_pr = (int*)(ws + 4608 + 4ull * B_ * P_);         // B*P*4
    float*  ce_neg     = (float*)(ws + 4608 + 8ull * B_ * P_);       // B*P*4

    dim3 gridBP((P_ + 255) / 256, B_);

    init_ws<<<1, 512, 0, stream>>>(best_key, n_pos, sums);
    match_kernel<<<gridBP, 256, 0, stream>>>(boxes, priors, prior_max, obj_for_pr, best_key);
    override_kernel<<<B_, 64, 0, stream>>>(prior_max, obj_for_pr, best_key);
    ce_kernel<<<gridBP, 256, 0, stream>>>(locs, scores, boxes, labels, priors,
                                          prior_max, obj_for_pr, ce_neg, n_pos, sums);
    topm_kernel<<<B_, 256, 0, stream>>>(ce_neg, n_pos, sums);
    final_kernel<<<1, 64, 0, stream>>>(n_pos, sums, out);
}

// Round 2
// 255.802 us; speedup vs baseline: 1.5724x; 1.5724x over previous
//
#include <hip/hip_runtime.h>
#include <math.h>

#define B_ 32
#define P_ 8732
#define C_ 81
#define K_ 16
#define THRESH 0.5f

// ws layout (bytes):
//   0     : best_key  u64[B*K]        (memset 0)
//   4096  : n_pos     int[B]          (memset 0)
//   4224  : pos_ce    double[B]       (memset 0)
//   4480  : l1        double[B]       (memset 0)
//   4736  : hard      double[B]       (written by topm, no init needed)
//   4992  : prior_max float[B*P]
//   +BP*4 : obj_for_prior int[B*P]
//   +BP*4 : ce_neg float[B*P]
#define OFF_NPOS   4096
#define OFF_POSCE  4224
#define OFF_L1     4480
#define OFF_HARD   4736
#define OFF_ARR    4992

// ---------------- match: per-prior max/argmax over K, per-object argmax over P ----------------
__global__ __launch_bounds__(256) void match_kernel(
    const float* __restrict__ boxes,   // [B,K,4] xyxy
    const float* __restrict__ priors,  // [P,4] cxcywh
    float* __restrict__ prior_max,     // [B,P]
    int* __restrict__ obj_for_prior,   // [B,P]
    unsigned long long* __restrict__ best_key) // [B,K]
{
    __shared__ float bx1[K_], by1[K_], bx2[K_], by2[K_], barea[K_];
    const int b = blockIdx.y;
    const int tid = threadIdx.x;
    if (tid < K_) {
        float x1 = boxes[(b * K_ + tid) * 4 + 0];
        float y1 = boxes[(b * K_ + tid) * 4 + 1];
        float x2 = boxes[(b * K_ + tid) * 4 + 2];
        float y2 = boxes[(b * K_ + tid) * 4 + 3];
        bx1[tid] = x1; by1[tid] = y1; bx2[tid] = x2; by2[tid] = y2;
        barea[tid] = (x2 - x1) * (y2 - y1);
    }
    __syncthreads();

    const int p = blockIdx.x * 256 + tid;
    const bool valid = (p < P_);
    float px1 = 0, py1 = 0, px2 = 0, py2 = 0, parea = 0;
    if (valid) {
        float4 pc = *(const float4*)(priors + (size_t)p * 4);
        px1 = pc.x - pc.z * 0.5f; py1 = pc.y - pc.w * 0.5f;
        px2 = pc.x + pc.z * 0.5f; py2 = pc.y + pc.w * 0.5f;
        parea = (px2 - px1) * (py2 - py1);
    }

    float best = -1.0f; int barg = 0;
    unsigned long long keys[K_];
#pragma unroll
    for (int k = 0; k < K_; ++k) {
        unsigned long long key = 0ULL;
        float ov = -1.0f;
        if (valid) {
            float ltx = fmaxf(bx1[k], px1), lty = fmaxf(by1[k], py1);
            float rbx = fminf(bx2[k], px2), rby = fminf(by2[k], py2);
            float w = fmaxf(rbx - ltx, 0.0f), h = fmaxf(rby - lty, 0.0f);
            float inter = w * h;
            ov = inter / (barea[k] + parea - inter);
            unsigned int bits = __float_as_uint(ov); // ov >= 0 -> monotone as uint
            key = ((unsigned long long)bits << 32) |
                  (unsigned long long)(0xFFFFFFFFu - (unsigned int)p); // smallest p wins ties
        }
        if (ov > best) { best = ov; barg = k; }  // strict > : first-index tie-break
        keys[k] = key;
    }
    if (valid) {
        prior_max[(size_t)b * P_ + p] = best;
        obj_for_prior[(size_t)b * P_ + p] = barg;
    }
#pragma unroll
    for (int k = 0; k < K_; ++k) {
        unsigned long long key = keys[k];
        for (int off = 32; off > 0; off >>= 1) {
            unsigned long long o = __shfl_down(key, off, 64);
            if (o > key) key = o;
        }
        if ((tid & 63) == 0) atomicMax(&best_key[b * K_ + k], key);
    }
}

// ---------------- override: each object claims its best prior ----------------
__global__ void override_kernel(float* __restrict__ prior_max,
                                int* __restrict__ obj_for_prior,
                                const unsigned long long* __restrict__ best_key) {
    int b = blockIdx.x;
    if (threadIdx.x == 0) {
        for (int k = 0; k < K_; ++k) {
            unsigned long long key = best_key[b * K_ + k];
            unsigned int p = 0xFFFFFFFFu - (unsigned int)(key & 0xFFFFFFFFu);
            obj_for_prior[(size_t)b * P_ + p] = k;
            prior_max[(size_t)b * P_ + p] = THRESH + 0.1f;
        }
    }
}

// ---------------- CE: one WAVE per (b,p) row — fully coalesced scores read ----------------
__global__ __launch_bounds__(256) void ce_kernel(
    const float* __restrict__ locs,    // [B,P,4]
    const float* __restrict__ scores,  // [B,P,C]
    const float* __restrict__ boxes,   // [B,K,4]
    const int* __restrict__ labels,    // [B,K]
    const float* __restrict__ priors,  // [P,4]
    const float* __restrict__ prior_max,
    const int* __restrict__ obj_for_prior,
    float* __restrict__ ce_neg,
    int* __restrict__ n_pos,           // [B]
    double* __restrict__ pos_ce,       // [B]
    double* __restrict__ l1_sum)       // [B]
{
    const int b = blockIdx.y;
    const int w = threadIdx.x >> 6;
    const int lane = threadIdx.x & 63;
    const int p = blockIdx.x * 4 + w;          // P_ = 4*2183 exactly
    const size_t bp = (size_t)b * P_ + p;

    const float pm = prior_max[bp];
    const bool pos = (pm >= THRESH);           // labels always >= 1
    const int obj = obj_for_prior[bp];
    const int lbl = pos ? labels[b * K_ + obj] : 0;

    const float* s = scores + bp * C_;
    const bool hi = (lane < C_ - 64);          // lanes 0..16 carry c=64..80
    float x0 = s[lane];
    float x1 = hi ? s[64 + lane] : -INFINITY;

    float m = fmaxf(x0, x1);
#pragma unroll
    for (int off = 1; off < 64; off <<= 1)
        m = fmaxf(m, __shfl_xor(m, off, 64));

    float e = __expf(x0 - m) + (hi ? __expf(x1 - m) : 0.0f);
#pragma unroll
    for (int off = 1; off < 64; off <<= 1)
        e += __shfl_xor(e, off, 64);

    const float sl = (lbl < 64) ? __shfl(x0, lbl, 64) : __shfl(x1, lbl - 64, 64);
    const float ce = (m + logf(e)) - sl;

    if (lane == 0) {
        ce_neg[bp] = pos ? 0.0f : ce;
        if (pos) {
            atomicAdd(&n_pos[b], 1);
            atomicAdd(&pos_ce[b], (double)ce);
            float4 bb = *(const float4*)(boxes + ((size_t)b * K_ + obj) * 4);
            float4 pc = *(const float4*)(priors + (size_t)p * 4);
            float cx = (bb.x + bb.z) * 0.5f, cy = (bb.y + bb.w) * 0.5f;
            float wd = bb.z - bb.x, ht = bb.w - bb.y;
            float gx = (cx - pc.x) / (pc.z / 10.0f);
            float gy = (cy - pc.y) / (pc.w / 10.0f);
            float gw = logf(wd / pc.z) * 5.0f;
            float gh = logf(ht / pc.w) * 5.0f;
            float4 pl = *(const float4*)(locs + bp * 4);
            float l1 = fabsf(pl.x - gx) + fabsf(pl.y - gy) + fabsf(pl.z - gw) + fabsf(pl.w - gh);
            atomicAdd(&l1_sum[b], (double)l1);
        }
    }
}

// ---------------- per-image top-M sum via bit-level binary search ----------------
__global__ __launch_bounds__(256) void topm_kernel(
    const float* __restrict__ ce_neg,
    const int* __restrict__ n_pos,
    double* __restrict__ hard)   // [B], written (not accumulated)
{
    const int b = blockIdx.x;
    const int tid = threadIdx.x;
    const int NV = (P_ + 255) / 256;  // 35
    __shared__ int s_cnt[4];
    __shared__ double s_sum[4];

    float v[NV];
    const float* src = ce_neg + (size_t)b * P_;
#pragma unroll
    for (int j = 0; j < NV; ++j) {
        int idx = tid + j * 256;
        v[j] = (idx < P_) ? src[idx] : -1.0f;
    }
    const int M = 3 * n_pos[b];

    double S_partial = 0.0;
    int c_partial = 0;
    float tval = 0.0f;
    bool sum_all = (M >= P_);

    if (!sum_all) {
        unsigned int lo = 0u, hi = 0x7f800000u;
        while (hi - lo > 1u) {
            unsigned int mid = (lo + hi) >> 1;
            float t = __uint_as_float(mid);
            int c = 0;
#pragma unroll
            for (int j = 0; j < NV; ++j) c += (v[j] >= t) ? 1 : 0;
            for (int off = 32; off > 0; off >>= 1) c += __shfl_down(c, off, 64);
            if ((tid & 63) == 0) s_cnt[tid >> 6] = c;
            __syncthreads();
            int tot = s_cnt[0] + s_cnt[1] + s_cnt[2] + s_cnt[3];
            __syncthreads();
            if (tot >= M) lo = mid; else hi = mid;
        }
        tval = __uint_as_float(lo);
#pragma unroll
        for (int j = 0; j < NV; ++j) {
            if (v[j] > tval) { c_partial++; S_partial += (double)v[j]; }
        }
    } else {
#pragma unroll
        for (int j = 0; j < NV; ++j) {
            if (v[j] >= 0.0f) S_partial += (double)v[j];
        }
    }

    for (int off = 32; off > 0; off >>= 1) {
        S_partial += __shfl_down(S_partial, off, 64);
        c_partial += __shfl_down(c_partial, off, 64);
    }
    if ((tid & 63) == 0) { s_cnt[tid >> 6] = c_partial; s_sum[tid >> 6] = S_partial; }
    __syncthreads();
    if (tid == 0) {
        int ctot = s_cnt[0] + s_cnt[1] + s_cnt[2] + s_cnt[3];
        double stot = s_sum[0] + s_sum[1] + s_sum[2] + s_sum[3];
        if (!sum_all) stot += (double)(M - ctot) * (double)tval;
        hard[b] = stot;
    }
}

// ---------------- final combine ----------------
__global__ void final_kernel(const int* __restrict__ n_pos,
                             const double* __restrict__ pos_ce,
                             const double* __restrict__ hard,
                             const double* __restrict__ l1_sum,
                             float* __restrict__ out) {
    if (threadIdx.x == 0) {
        int tot = 0;
        double sc = 0.0, sh = 0.0, sl = 0.0;
        for (int b = 0; b < B_; ++b) {
            tot += n_pos[b];
            sc += pos_ce[b]; sh += hard[b]; sl += l1_sum[b];
        }
        double n = (double)tot;
        double class_loss = (sc + sh) / n;
        double box_loss = sl / (n * 4.0);
        out[0] = (float)(class_loss + box_loss);
    }
}

extern "C" void kernel_launch(void* const* d_in, const int* in_sizes, int n_in,
                              void* d_out, int out_size, void* d_ws, size_t ws_size,
                              hipStream_t stream) {
    const float* locs   = (const float*)d_in[0];
    const float* scores = (const float*)d_in[1];
    const float* boxes  = (const float*)d_in[2];
    const int*   labels = (const int*)d_in[3];
    const float* priors = (const float*)d_in[4];
    float* out = (float*)d_out;

    char* ws = (char*)d_ws;
    unsigned long long* best_key = (unsigned long long*)ws;
    int*    n_pos  = (int*)(ws + OFF_NPOS);
    double* pos_ce = (double*)(ws + OFF_POSCE);
    double* l1_sum = (double*)(ws + OFF_L1);
    double* hard   = (double*)(ws + OFF_HARD);
    float*  prior_max  = (float*)(ws + OFF_ARR);
    int*    obj_for_pr = (int*)(ws + OFF_ARR + 4ull * B_ * P_);
    float*  ce_neg     = (float*)(ws + OFF_ARR + 8ull * B_ * P_);

    // zero best_key, n_pos, pos_ce, l1_sum (hard is written unconditionally)
    hipMemsetAsync(ws, 0, OFF_ARR, stream);

    dim3 gridBP((P_ + 255) / 256, B_);
    match_kernel<<<gridBP, 256, 0, stream>>>(boxes, priors, prior_max, obj_for_pr, best_key);
    override_kernel<<<B_, 64, 0, stream>>>(prior_max, obj_for_pr, best_key);
    ce_kernel<<<dim3(P_ / 4, B_), 256, 0, stream>>>(locs, scores, boxes, labels, priors,
                                                    prior_max, obj_for_pr, ce_neg,
                                                    n_pos, pos_ce, l1_sum);
    topm_kernel<<<B_, 256, 0, stream>>>(ce_neg, n_pos, hard);
    final_kernel<<<1, 64, 0, stream>>>(n_pos, pos_ce, hard, l1_sum, out);
}

// Round 3
// 218.458 us; speedup vs baseline: 1.8413x; 1.1709x over previous
//
#include <hip/hip_runtime.h>
#include <math.h>

#define B_ 32
#define P_ 8732
#define C_ 81
#define K_ 16
#define THRESH 0.5f
#define NBLK_X 35          // ceil(P_/256) match-kernel blocks per image

// ws layout (bytes), all regions fully written before read (poison-safe):
//   0       : part     u64[B][NBLK_X][K]   = 143360 B   (match -> winners)
//   143360  : winners  int[B][K]           = 2048 B
//   145408  : n_pos    int[B]              = 128 B      (zeroed by winners_kernel)
//   145536  : pos_ce   double[B]           = 256 B      (zeroed by winners_kernel)
//   145792  : l1_sum   double[B]           = 256 B      (zeroed by winners_kernel)
//   146048  : hard     double[B]           = 256 B      (written by topm)
//   146304  : prior_max float[B*P]
//   +BP*4   : obj_for_prior int[B*P]
//   +BP*4   : ce_neg float[B*P]
#define OFF_WIN    143360
#define OFF_NPOS   145408
#define OFF_POSCE  145536
#define OFF_L1     145792
#define OFF_HARD   146048
#define OFF_ARR    146304

// ---------------- match: per-prior max/argmax over K + per-block object partials ----------------
__global__ __launch_bounds__(256) void match_kernel(
    const float* __restrict__ boxes,   // [B,K,4] xyxy
    const float* __restrict__ priors,  // [P,4] cxcywh
    float* __restrict__ prior_max,     // [B,P]
    int* __restrict__ obj_for_prior,   // [B,P]
    unsigned long long* __restrict__ part) // [B][NBLK_X][K]
{
    __shared__ float bx1[K_], by1[K_], bx2[K_], by2[K_], barea[K_];
    __shared__ unsigned long long s_part[4][K_];
    const int b = blockIdx.y;
    const int tid = threadIdx.x;
    if (tid < K_) {
        float x1 = boxes[(b * K_ + tid) * 4 + 0];
        float y1 = boxes[(b * K_ + tid) * 4 + 1];
        float x2 = boxes[(b * K_ + tid) * 4 + 2];
        float y2 = boxes[(b * K_ + tid) * 4 + 3];
        bx1[tid] = x1; by1[tid] = y1; bx2[tid] = x2; by2[tid] = y2;
        barea[tid] = (x2 - x1) * (y2 - y1);
    }
    __syncthreads();

    const int p = blockIdx.x * 256 + tid;
    const bool valid = (p < P_);
    float px1 = 0, py1 = 0, px2 = 0, py2 = 0, parea = 0;
    if (valid) {
        float4 pc = *(const float4*)(priors + (size_t)p * 4);
        px1 = pc.x - pc.z * 0.5f; py1 = pc.y - pc.w * 0.5f;
        px2 = pc.x + pc.z * 0.5f; py2 = pc.y + pc.w * 0.5f;
        parea = (px2 - px1) * (py2 - py1);
    }

    float best = -1.0f; int barg = 0;
    unsigned long long keys[K_];
#pragma unroll
    for (int k = 0; k < K_; ++k) {
        unsigned long long key = 0ULL;
        float ov = -1.0f;
        if (valid) {
            float ltx = fmaxf(bx1[k], px1), lty = fmaxf(by1[k], py1);
            float rbx = fminf(bx2[k], px2), rby = fminf(by2[k], py2);
            float w = fmaxf(rbx - ltx, 0.0f), h = fmaxf(rby - lty, 0.0f);
            float inter = w * h;
            ov = inter / (barea[k] + parea - inter);
            unsigned int bits = __float_as_uint(ov); // ov >= 0 -> monotone as uint
            key = ((unsigned long long)bits << 32) |
                  (unsigned long long)(0xFFFFFFFFu - (unsigned int)p); // smallest p wins ties
        }
        if (ov > best) { best = ov; barg = k; }  // strict > : first-index tie-break
        keys[k] = key;
    }
    if (valid) {
        prior_max[(size_t)b * P_ + p] = best;
        obj_for_prior[(size_t)b * P_ + p] = barg;
    }
    // wave-reduce each object's key -> LDS -> block partial (no global atomics, no init)
#pragma unroll
    for (int k = 0; k < K_; ++k) {
        unsigned long long key = keys[k];
        for (int off = 32; off > 0; off >>= 1) {
            unsigned long long o = __shfl_down(key, off, 64);
            if (o > key) key = o;
        }
        if ((tid & 63) == 0) s_part[tid >> 6][k] = key;
    }
    __syncthreads();
    if (tid < K_) {
        unsigned long long m0 = s_part[0][tid], m1 = s_part[1][tid];
        unsigned long long m2 = s_part[2][tid], m3 = s_part[3][tid];
        unsigned long long m = m0 > m1 ? m0 : m1;
        unsigned long long n = m2 > m3 ? m2 : m3;
        if (n > m) m = n;
        part[((size_t)b * NBLK_X + blockIdx.x) * K_ + tid] = m;
    }
}

// ---------------- winners: reduce partials -> winner prior per object; zero accumulators ----------------
__global__ void winners_kernel(const unsigned long long* __restrict__ part,
                               int* __restrict__ winners,
                               int* __restrict__ n_pos,
                               double* __restrict__ pos_ce,
                               double* __restrict__ l1_sum) {
    const int b = blockIdx.x;
    const int t = threadIdx.x;
    if (t < K_) {
        unsigned long long m = 0ULL;
#pragma unroll
        for (int i = 0; i < NBLK_X; ++i) {
            unsigned long long v = part[((size_t)b * NBLK_X + i) * K_ + t];
            if (v > m) m = v;
        }
        winners[b * K_ + t] = (int)(0xFFFFFFFFu - (unsigned int)(m & 0xFFFFFFFFu));
    } else if (t == 16) { n_pos[b] = 0; }
    else if (t == 17) { pos_ce[b] = 0.0; }
    else if (t == 18) { l1_sum[b] = 0.0; }
}

// ---------------- CE: quarter-wave (16 lanes) per row; override folded in ----------------
__global__ __launch_bounds__(256) void ce_kernel(
    const float* __restrict__ locs,    // [B,P,4]
    const float* __restrict__ scores,  // [B,P,C]
    const float* __restrict__ boxes,   // [B,K,4]
    const int* __restrict__ labels,    // [B,K]
    const float* __restrict__ priors,  // [P,4]
    const float* __restrict__ prior_max,
    const int* __restrict__ obj_for_prior,
    const int* __restrict__ winners,   // [B,K]
    float* __restrict__ ce_neg,
    int* __restrict__ n_pos,           // [B]
    double* __restrict__ pos_ce,       // [B]
    double* __restrict__ l1_sum)       // [B]
{
    const int b = blockIdx.y;
    const int sub = threadIdx.x & 15;
    const int p_raw = blockIdx.x * 16 + (threadIdx.x >> 4);
    const bool valid = (p_raw < P_);
    const int p = valid ? p_raw : P_ - 1;
    const size_t bp = (size_t)b * P_ + p;

    // override: max k whose winner prior == p (matches sequential last-wins scatter)
    int ok = -1;
#pragma unroll
    for (int k = 0; k < K_; ++k)
        if (winners[b * K_ + k] == p) ok = k;

    bool pos; int obj;
    if (ok >= 0) { pos = true; obj = ok; }
    else { obj = obj_for_prior[bp]; pos = (prior_max[bp] >= THRESH); }
    const int lbl = pos ? labels[b * K_ + obj] : 0;

    const float* s = scores + bp * C_ + sub;
    float x0 = s[0], x1 = s[16], x2 = s[32], x3 = s[48], x4 = s[64];
    float x5 = (sub == 0) ? s[80] : -INFINITY;

    float m = fmaxf(fmaxf(fmaxf(x0, x1), fmaxf(x2, x3)), fmaxf(x4, x5));
#pragma unroll
    for (int off = 1; off < 16; off <<= 1)
        m = fmaxf(m, __shfl_xor(m, off, 64));

    float e = __expf(x0 - m) + __expf(x1 - m) + __expf(x2 - m) +
              __expf(x3 - m) + __expf(x4 - m) + __expf(x5 - m);
    float sl = (sub      == lbl) ? x0 : 0.0f;
    sl += (sub + 16 == lbl) ? x1 : 0.0f;
    sl += (sub + 32 == lbl) ? x2 : 0.0f;
    sl += (sub + 48 == lbl) ? x3 : 0.0f;
    sl += (sub + 64 == lbl) ? x4 : 0.0f;
    sl += (sub == 0 && lbl == 80) ? x5 : 0.0f;
#pragma unroll
    for (int off = 1; off < 16; off <<= 1) {
        e  += __shfl_xor(e, off, 64);
        sl += __shfl_xor(sl, off, 64);
    }
    const float ce = (m + logf(e)) - sl;

    if (sub == 0 && valid) {
        ce_neg[bp] = pos ? 0.0f : ce;
        if (pos) {
            atomicAdd(&n_pos[b], 1);
            atomicAdd(&pos_ce[b], (double)ce);
            float4 bb = *(const float4*)(boxes + ((size_t)b * K_ + obj) * 4);
            float4 pc = *(const float4*)(priors + (size_t)p * 4);
            float cx = (bb.x + bb.z) * 0.5f, cy = (bb.y + bb.w) * 0.5f;
            float wd = bb.z - bb.x, ht = bb.w - bb.y;
            float gx = (cx - pc.x) / (pc.z / 10.0f);
            float gy = (cy - pc.y) / (pc.w / 10.0f);
            float gw = logf(wd / pc.z) * 5.0f;
            float gh = logf(ht / pc.w) * 5.0f;
            float4 pl = *(const float4*)(locs + bp * 4);
            float l1 = fabsf(pl.x - gx) + fabsf(pl.y - gy) + fabsf(pl.z - gw) + fabsf(pl.w - gh);
            atomicAdd(&l1_sum[b], (double)l1);
        }
    }
}

// ---------------- per-image top-M sum via bit-level binary search ----------------
__global__ __launch_bounds__(256) void topm_kernel(
    const float* __restrict__ ce_neg,
    const int* __restrict__ n_pos,
    double* __restrict__ hard)   // [B]
{
    const int b = blockIdx.x;
    const int tid = threadIdx.x;
    const int NV = (P_ + 255) / 256;  // 35
    __shared__ int s_cnt[4];
    __shared__ double s_sum[4];

    float v[NV];
    const float* src = ce_neg + (size_t)b * P_;
#pragma unroll
    for (int j = 0; j < NV; ++j) {
        int idx = tid + j * 256;
        v[j] = (idx < P_) ? src[idx] : -1.0f;
    }
    const int M = 3 * n_pos[b];

    double S_partial = 0.0;
    int c_partial = 0;
    float tval = 0.0f;
    bool sum_all = (M >= P_);

    if (!sum_all) {
        unsigned int lo = 0u, hi = 0x7f800000u;
        while (hi - lo > 1u) {
            unsigned int mid = (lo + hi) >> 1;
            float t = __uint_as_float(mid);
            int c = 0;
#pragma unroll
            for (int j = 0; j < NV; ++j) c += (v[j] >= t) ? 1 : 0;
            for (int off = 32; off > 0; off >>= 1) c += __shfl_down(c, off, 64);
            if ((tid & 63) == 0) s_cnt[tid >> 6] = c;
            __syncthreads();
            int tot = s_cnt[0] + s_cnt[1] + s_cnt[2] + s_cnt[3];
            __syncthreads();
            if (tot >= M) lo = mid; else hi = mid;
        }
        tval = __uint_as_float(lo);
#pragma unroll
        for (int j = 0; j < NV; ++j) {
            if (v[j] > tval) { c_partial++; S_partial += (double)v[j]; }
        }
    } else {
#pragma unroll
        for (int j = 0; j < NV; ++j) {
            if (v[j] >= 0.0f) S_partial += (double)v[j];
        }
    }

    for (int off = 32; off > 0; off >>= 1) {
        S_partial += __shfl_down(S_partial, off, 64);
        c_partial += __shfl_down(c_partial, off, 64);
    }
    if ((tid & 63) == 0) { s_cnt[tid >> 6] = c_partial; s_sum[tid >> 6] = S_partial; }
    __syncthreads();
    if (tid == 0) {
        int ctot = s_cnt[0] + s_cnt[1] + s_cnt[2] + s_cnt[3];
        double stot = s_sum[0] + s_sum[1] + s_sum[2] + s_sum[3];
        if (!sum_all) stot += (double)(M - ctot) * (double)tval;
        hard[b] = stot;
    }
}

// ---------------- final combine ----------------
__global__ void final_kernel(const int* __restrict__ n_pos,
                             const double* __restrict__ pos_ce,
                             const double* __restrict__ hard,
                             const double* __restrict__ l1_sum,
                             float* __restrict__ out) {
    if (threadIdx.x == 0) {
        int tot = 0;
        double sc = 0.0, sh = 0.0, sl = 0.0;
        for (int b = 0; b < B_; ++b) {
            tot += n_pos[b];
            sc += pos_ce[b]; sh += hard[b]; sl += l1_sum[b];
        }
        double n = (double)tot;
        double class_loss = (sc + sh) / n;
        double box_loss = sl / (n * 4.0);
        out[0] = (float)(class_loss + box_loss);
    }
}

extern "C" void kernel_launch(void* const* d_in, const int* in_sizes, int n_in,
                              void* d_out, int out_size, void* d_ws, size_t ws_size,
                              hipStream_t stream) {
    const float* locs   = (const float*)d_in[0];
    const float* scores = (const float*)d_in[1];
    const float* boxes  = (const float*)d_in[2];
    const int*   labels = (const int*)d_in[3];
    const float* priors = (const float*)d_in[4];
    float* out = (float*)d_out;

    char* ws = (char*)d_ws;
    unsigned long long* part = (unsigned long long*)ws;
    int*    winners = (int*)(ws + OFF_WIN);
    int*    n_pos   = (int*)(ws + OFF_NPOS);
    double* pos_ce  = (double*)(ws + OFF_POSCE);
    double* l1_sum  = (double*)(ws + OFF_L1);
    double* hard    = (double*)(ws + OFF_HARD);
    float*  prior_max  = (float*)(ws + OFF_ARR);
    int*    obj_for_pr = (int*)(ws + OFF_ARR + 4ull * B_ * P_);
    float*  ce_neg     = (float*)(ws + OFF_ARR + 8ull * B_ * P_);

    match_kernel<<<dim3(NBLK_X, B_), 256, 0, stream>>>(boxes, priors, prior_max,
                                                       obj_for_pr, part);
    winners_kernel<<<B_, 64, 0, stream>>>(part, winners, n_pos, pos_ce, l1_sum);
    ce_kernel<<<dim3((P_ + 15) / 16, B_), 256, 0, stream>>>(locs, scores, boxes, labels,
                                                            priors, prior_max, obj_for_pr,
                                                            winners, ce_neg,
                                                            n_pos, pos_ce, l1_sum);
    topm_kernel<<<B_, 256, 0, stream>>>(ce_neg, n_pos, hard);
    final_kernel<<<1, 64, 0, stream>>>(n_pos, pos_ce, hard, l1_sum, out);
}

// Round 4
// 213.622 us; speedup vs baseline: 1.8829x; 1.0226x over previous
//
#include <hip/hip_runtime.h>
#include <math.h>

#define B_ 32
#define P_ 8732
#define C_ 81
#define K_ 16
#define THRESH 0.5f
#define NBLK_X 35          // ceil(P_/256) match-kernel blocks per image

// ws layout (bytes), all regions fully written before read (poison-safe):
//   0       : part   u64[B][NBLK_X][K] = 143360
//   143360  : n_pos  int[B]            (zeroed by winners_kernel)
//   143488  : pos_ce double[B]         (zeroed by winners_kernel)
//   143744  : l1_sum double[B]         (zeroed by winners_kernel)
//   144000  : hard   double[B]         (written by topm)
//   144256  : cls    int[B*P]          (match writes all, winners overrides)
//   +BP*4   : obj_for_prior int[B*P]
//   +BP*4   : ce_neg float[B*P]
#define OFF_NPOS   143360
#define OFF_POSCE  143488
#define OFF_L1     143744
#define OFF_HARD   144000
#define OFF_ARR    144256

// ---- DPP 16-lane reductions (result in lane 15 of each quarter; VALU pipe, no DS) ----
__device__ __forceinline__ float dpp_red_max16(float x) {
    int y;
    y = __builtin_amdgcn_update_dpp(__float_as_int(x), __float_as_int(x), 0x111, 0xF, 0xF, false);
    x = fmaxf(x, __int_as_float(y));
    y = __builtin_amdgcn_update_dpp(__float_as_int(x), __float_as_int(x), 0x112, 0xF, 0xF, false);
    x = fmaxf(x, __int_as_float(y));
    y = __builtin_amdgcn_update_dpp(__float_as_int(x), __float_as_int(x), 0x114, 0xF, 0xF, false);
    x = fmaxf(x, __int_as_float(y));
    y = __builtin_amdgcn_update_dpp(__float_as_int(x), __float_as_int(x), 0x118, 0xF, 0xF, false);
    x = fmaxf(x, __int_as_float(y));
    return x;                       // lane15 = max of 16; others = prefix max
}
__device__ __forceinline__ float dpp_red_sum16(float x) {
    int y;
    y = __builtin_amdgcn_update_dpp(0, __float_as_int(x), 0x111, 0xF, 0xF, false);
    x += __int_as_float(y);
    y = __builtin_amdgcn_update_dpp(0, __float_as_int(x), 0x112, 0xF, 0xF, false);
    x += __int_as_float(y);
    y = __builtin_amdgcn_update_dpp(0, __float_as_int(x), 0x114, 0xF, 0xF, false);
    x += __int_as_float(y);
    y = __builtin_amdgcn_update_dpp(0, __float_as_int(x), 0x118, 0xF, 0xF, false);
    x += __int_as_float(y);
    return x;                       // lane15 = sum of 16 (old=0 for shifted-in lanes)
}

// ---------------- match: per-prior max/argmax over K + per-block object partials ----------------
__global__ __launch_bounds__(256) void match_kernel(
    const float* __restrict__ boxes,   // [B,K,4] xyxy
    const int* __restrict__ labels,    // [B,K]
    const float* __restrict__ priors,  // [P,4] cxcywh
    int* __restrict__ cls,             // [B,P] label-or-0 after threshold
    int* __restrict__ obj_for_prior,   // [B,P]
    unsigned long long* __restrict__ part) // [B][NBLK_X][K]
{
    __shared__ float bx1[K_], by1[K_], bx2[K_], by2[K_], barea[K_];
    __shared__ int s_lbl[K_];
    __shared__ unsigned long long s_part[4][K_];
    const int b = blockIdx.y;
    const int tid = threadIdx.x;
    if (tid < K_) {
        float x1 = boxes[(b * K_ + tid) * 4 + 0];
        float y1 = boxes[(b * K_ + tid) * 4 + 1];
        float x2 = boxes[(b * K_ + tid) * 4 + 2];
        float y2 = boxes[(b * K_ + tid) * 4 + 3];
        bx1[tid] = x1; by1[tid] = y1; bx2[tid] = x2; by2[tid] = y2;
        barea[tid] = (x2 - x1) * (y2 - y1);
        s_lbl[tid] = labels[b * K_ + tid];
    }
    __syncthreads();

    const int p = blockIdx.x * 256 + tid;
    const bool valid = (p < P_);
    float px1 = 0, py1 = 0, px2 = 0, py2 = 0, parea = 0;
    if (valid) {
        float4 pc = *(const float4*)(priors + (size_t)p * 4);
        px1 = pc.x - pc.z * 0.5f; py1 = pc.y - pc.w * 0.5f;
        px2 = pc.x + pc.z * 0.5f; py2 = pc.y + pc.w * 0.5f;
        parea = (px2 - px1) * (py2 - py1);
    }

    float best = -1.0f; int barg = 0;
    unsigned long long keys[K_];
#pragma unroll
    for (int k = 0; k < K_; ++k) {
        unsigned long long key = 0ULL;
        float ov = -1.0f;
        if (valid) {
            float ltx = fmaxf(bx1[k], px1), lty = fmaxf(by1[k], py1);
            float rbx = fminf(bx2[k], px2), rby = fminf(by2[k], py2);
            float w = fmaxf(rbx - ltx, 0.0f), h = fmaxf(rby - lty, 0.0f);
            float inter = w * h;
            ov = inter / (barea[k] + parea - inter);
            unsigned int bits = __float_as_uint(ov); // ov >= 0 -> monotone as uint
            key = ((unsigned long long)bits << 32) |
                  (unsigned long long)(0xFFFFFFFFu - (unsigned int)p); // smallest p wins ties
        }
        if (ov > best) { best = ov; barg = k; }  // strict > : first-index tie-break
        keys[k] = key;
    }
    if (valid) {
        cls[(size_t)b * P_ + p] = (best >= THRESH) ? s_lbl[barg] : 0;
        obj_for_prior[(size_t)b * P_ + p] = barg;
    }
#pragma unroll
    for (int k = 0; k < K_; ++k) {
        unsigned long long key = keys[k];
        for (int off = 32; off > 0; off >>= 1) {
            unsigned long long o = __shfl_down(key, off, 64);
            if (o > key) key = o;
        }
        if ((tid & 63) == 0) s_part[tid >> 6][k] = key;
    }
    __syncthreads();
    if (tid < K_) {
        unsigned long long m0 = s_part[0][tid], m1 = s_part[1][tid];
        unsigned long long m2 = s_part[2][tid], m3 = s_part[3][tid];
        unsigned long long m = m0 > m1 ? m0 : m1;
        unsigned long long n = m2 > m3 ? m2 : m3;
        if (n > m) m = n;
        part[((size_t)b * NBLK_X + blockIdx.x) * K_ + tid] = m;
    }
}

// ---- winners: reduce partials -> apply object override scatter; zero accumulators ----
__global__ void winners_kernel(const unsigned long long* __restrict__ part,
                               const int* __restrict__ labels,
                               int* __restrict__ cls,
                               int* __restrict__ obj_for_prior,
                               int* __restrict__ n_pos,
                               double* __restrict__ pos_ce,
                               double* __restrict__ l1_sum) {
    const int b = blockIdx.x;
    const int t = threadIdx.x;
    __shared__ int s_win[K_];
    if (t < K_) {
        unsigned long long m = 0ULL;
#pragma unroll
        for (int i = 0; i < NBLK_X; ++i) {
            unsigned long long v = part[((size_t)b * NBLK_X + i) * K_ + t];
            if (v > m) m = v;
        }
        s_win[t] = (int)(0xFFFFFFFFu - (unsigned int)(m & 0xFFFFFFFFu));
    }
    __syncthreads();
    if (t == 0) {
        // sequential last-wins scatter (matches .at[].set with duplicate indices)
        for (int k = 0; k < K_; ++k) {
            int p = s_win[k];
            obj_for_prior[(size_t)b * P_ + p] = k;
            cls[(size_t)b * P_ + p] = labels[b * K_ + k];  // forced positive (labels >= 1)
        }
    } else if (t == 1) { n_pos[b] = 0; }
    else if (t == 2) { pos_ce[b] = 0.0; }
    else if (t == 3) { l1_sum[b] = 0.0; }
}

// ---- CE: 16 lanes/row, 2 rows/quarter, float4 loads, DPP reductions ----
__device__ __forceinline__ void pos_accum(
    int b, int p, size_t bp, float ce, int obj,
    const float* __restrict__ locs, const float* __restrict__ boxes,
    const float* __restrict__ priors,
    int* __restrict__ n_pos, double* __restrict__ pos_ce, double* __restrict__ l1_sum)
{
    atomicAdd(&n_pos[b], 1);
    atomicAdd(&pos_ce[b], (double)ce);
    float4 bb = *(const float4*)(boxes + ((size_t)b * K_ + obj) * 4);
    float4 pc = *(const float4*)(priors + (size_t)p * 4);
    float cx = (bb.x + bb.z) * 0.5f, cy = (bb.y + bb.w) * 0.5f;
    float wd = bb.z - bb.x, ht = bb.w - bb.y;
    float gx = (cx - pc.x) / (pc.z / 10.0f);
    float gy = (cy - pc.y) / (pc.w / 10.0f);
    float gw = logf(wd / pc.z) * 5.0f;
    float gh = logf(ht / pc.w) * 5.0f;
    float4 pl = *(const float4*)(locs + bp * 4);
    float l1 = fabsf(pl.x - gx) + fabsf(pl.y - gy) + fabsf(pl.z - gw) + fabsf(pl.w - gh);
    atomicAdd(&l1_sum[b], (double)l1);
}

__global__ __launch_bounds__(256) void ce_kernel(
    const float* __restrict__ locs,    // [B,P,4]
    const float* __restrict__ scores,  // [B,P,C]
    const float* __restrict__ boxes,   // [B,K,4]
    const float* __restrict__ priors,  // [P,4]
    const int* __restrict__ cls,       // [B,P]
    const int* __restrict__ obj_for_prior,
    float* __restrict__ ce_neg,
    int* __restrict__ n_pos,
    double* __restrict__ pos_ce,
    double* __restrict__ l1_sum)
{
    const int b = blockIdx.y;
    const int tid = threadIdx.x;
    const int sub = tid & 15;
    const int pA_raw = blockIdx.x * 32 + ((tid >> 4) << 1);  // 32 rows/block
    const int pB_raw = pA_raw + 1;
    const bool vA = (pA_raw < P_), vB = (pB_raw < P_);
    const int pA = vA ? pA_raw : (P_ - 1);
    const int pB = vB ? pB_raw : (P_ - 1);
    const size_t bpA = (size_t)b * P_ + pA;
    const size_t bpB = (size_t)b * P_ + pB;

    // ---- loads: 16B vector + dword + predicated dword per row ----
    const float* sA = scores + bpA * C_;
    const float* sB = scores + bpB * C_;
    float4 a4, b4;
    __builtin_memcpy(&a4, sA + 4 * sub, 16);   // c = 4sub..4sub+3 (rows are 324B -> align 4)
    __builtin_memcpy(&b4, sB + 4 * sub, 16);
    const float a1 = sA[64 + sub];             // c = 64..79
    const float b1 = sB[64 + sub];
    float a2 = -INFINITY, b2 = -INFINITY;
    if (sub == 0) { a2 = sA[80]; b2 = sB[80]; }
    const int lblA = cls[bpA];                 // broadcast within quarter
    const int lblB = cls[bpB];

    // ---- max ----
    float mA = fmaxf(fmaxf(fmaxf(a4.x, a4.y), fmaxf(a4.z, a4.w)), fmaxf(a1, a2));
    float mB = fmaxf(fmaxf(fmaxf(b4.x, b4.y), fmaxf(b4.z, b4.w)), fmaxf(b1, b2));
    mA = dpp_red_max16(mA);
    mB = dpp_red_max16(mB);
    const int lane15 = (tid & 48) | 15;
    mA = __shfl(mA, lane15, 64);               // broadcast group max
    mB = __shfl(mB, lane15, 64);

    // ---- sum exp ----
    float eA = __expf(a4.x - mA) + __expf(a4.y - mA) + __expf(a4.z - mA) +
               __expf(a4.w - mA) + __expf(a1 - mA) + __expf(a2 - mA);   // exp(-inf)=0
    float eB = __expf(b4.x - mB) + __expf(b4.y - mB) + __expf(b4.z - mB) +
               __expf(b4.w - mB) + __expf(b1 - mB) + __expf(b2 - mB);
    eA = dpp_red_sum16(eA);                    // lane15 = total
    eB = dpp_red_sum16(eB);

    // ---- label score: single bpermute from owning lane ----
    const int ownA = (lblA < 64) ? (lblA >> 2) : ((lblA < 80) ? (lblA - 64) : 0);
    const int ownB = (lblB < 64) ? (lblB >> 2) : ((lblB < 80) ? (lblB - 64) : 0);
    const int iA = lblA & 3, iB = lblB & 3;
    const float candA = (lblA < 64)
        ? ((iA == 0) ? a4.x : (iA == 1) ? a4.y : (iA == 2) ? a4.z : a4.w)
        : ((lblA < 80) ? a1 : a2);
    const float candB = (lblB < 64)
        ? ((iB == 0) ? b4.x : (iB == 1) ? b4.y : (iB == 2) ? b4.z : b4.w)
        : ((lblB < 80) ? b1 : b2);
    const float slA = __shfl(candA, (tid & 48) | ownA, 64);
    const float slB = __shfl(candB, (tid & 48) | ownB, 64);

    if (sub == 15) {
        const float ceA = mA + logf(eA) - slA;
        const float ceB = mB + logf(eB) - slB;
        if (vA) {
            const bool pos = (lblA != 0);
            ce_neg[bpA] = pos ? 0.0f : ceA;
            if (pos) pos_accum(b, pA, bpA, ceA, obj_for_prior[bpA],
                               locs, boxes, priors, n_pos, pos_ce, l1_sum);
        }
        if (vB) {
            const bool pos = (lblB != 0);
            ce_neg[bpB] = pos ? 0.0f : ceB;
            if (pos) pos_accum(b, pB, bpB, ceB, obj_for_prior[bpB],
                               locs, boxes, priors, n_pos, pos_ce, l1_sum);
        }
    }
}

// ---------------- per-image top-M sum via bit-level binary search ----------------
__global__ __launch_bounds__(256) void topm_kernel(
    const float* __restrict__ ce_neg,
    const int* __restrict__ n_pos,
    double* __restrict__ hard)   // [B]
{
    const int b = blockIdx.x;
    const int tid = threadIdx.x;
    const int NV = (P_ + 255) / 256;  // 35
    __shared__ int s_cnt[32][4];      // one slot per binary-search iteration
    __shared__ int s_fc[4];
    __shared__ double s_fs[4];

    float v[NV];
    const float* src = ce_neg + (size_t)b * P_;
#pragma unroll
    for (int j = 0; j < NV; ++j) {
        int idx = tid + j * 256;
        v[j] = (idx < P_) ? src[idx] : -1.0f;
    }
    const int M = 3 * n_pos[b];

    double S_partial = 0.0;
    int c_partial = 0;
    float tval = 0.0f;
    bool sum_all = (M >= P_);

    if (!sum_all) {
        unsigned int lo = 0u, hi = 0x7f800000u;
        int it = 0;
        while (hi - lo > 1u) {
            unsigned int mid = (lo + hi) >> 1;
            float t = __uint_as_float(mid);
            int c = 0;
#pragma unroll
            for (int j = 0; j < NV; ++j) c += (v[j] >= t) ? 1 : 0;
            for (int off = 32; off > 0; off >>= 1) c += __shfl_down(c, off, 64);
            if ((tid & 63) == 0) s_cnt[it][tid >> 6] = c;
            __syncthreads();
            int tot = s_cnt[it][0] + s_cnt[it][1] + s_cnt[it][2] + s_cnt[it][3];
            if (tot >= M) lo = mid; else hi = mid;
            ++it;   // fresh slot -> no second barrier needed
        }
        tval = __uint_as_float(lo);
#pragma unroll
        for (int j = 0; j < NV; ++j) {
            if (v[j] > tval) { c_partial++; S_partial += (double)v[j]; }
        }
    } else {
#pragma unroll
        for (int j = 0; j < NV; ++j) {
            if (v[j] >= 0.0f) S_partial += (double)v[j];
        }
    }

    for (int off = 32; off > 0; off >>= 1) {
        S_partial += __shfl_down(S_partial, off, 64);
        c_partial += __shfl_down(c_partial, off, 64);
    }
    if ((tid & 63) == 0) { s_fc[tid >> 6] = c_partial; s_fs[tid >> 6] = S_partial; }
    __syncthreads();
    if (tid == 0) {
        int ctot = s_fc[0] + s_fc[1] + s_fc[2] + s_fc[3];
        double stot = s_fs[0] + s_fs[1] + s_fs[2] + s_fs[3];
        if (!sum_all) stot += (double)(M - ctot) * (double)tval;
        hard[b] = stot;
    }
}

// ---------------- final combine ----------------
__global__ void final_kernel(const int* __restrict__ n_pos,
                             const double* __restrict__ pos_ce,
                             const double* __restrict__ hard,
                             const double* __restrict__ l1_sum,
                             float* __restrict__ out) {
    if (threadIdx.x == 0) {
        int tot = 0;
        double sc = 0.0, sh = 0.0, sl = 0.0;
        for (int b = 0; b < B_; ++b) {
            tot += n_pos[b];
            sc += pos_ce[b]; sh += hard[b]; sl += l1_sum[b];
        }
        double n = (double)tot;
        double class_loss = (sc + sh) / n;
        double box_loss = sl / (n * 4.0);
        out[0] = (float)(class_loss + box_loss);
    }
}

extern "C" void kernel_launch(void* const* d_in, const int* in_sizes, int n_in,
                              void* d_out, int out_size, void* d_ws, size_t ws_size,
                              hipStream_t stream) {
    const float* locs   = (const float*)d_in[0];
    const float* scores = (const float*)d_in[1];
    const float* boxes  = (const float*)d_in[2];
    const int*   labels = (const int*)d_in[3];
    const float* priors = (const float*)d_in[4];
    float* out = (float*)d_out;

    char* ws = (char*)d_ws;
    unsigned long long* part = (unsigned long long*)ws;
    int*    n_pos   = (int*)(ws + OFF_NPOS);
    double* pos_ce  = (double*)(ws + OFF_POSCE);
    double* l1_sum  = (double*)(ws + OFF_L1);
    double* hard    = (double*)(ws + OFF_HARD);
    int*    cls     = (int*)(ws + OFF_ARR);
    int*    obj_for_pr = (int*)(ws + OFF_ARR + 4ull * B_ * P_);
    float*  ce_neg     = (float*)(ws + OFF_ARR + 8ull * B_ * P_);

    match_kernel<<<dim3(NBLK_X, B_), 256, 0, stream>>>(boxes, labels, priors,
                                                       cls, obj_for_pr, part);
    winners_kernel<<<B_, 64, 0, stream>>>(part, labels, cls, obj_for_pr,
                                          n_pos, pos_ce, l1_sum);
    ce_kernel<<<dim3((P_ + 31) / 32, B_), 256, 0, stream>>>(locs, scores, boxes, priors,
                                                            cls, obj_for_pr, ce_neg,
                                                            n_pos, pos_ce, l1_sum);
    topm_kernel<<<B_, 256, 0, stream>>>(ce_neg, n_pos, hard);
    final_kernel<<<1, 64, 0, stream>>>(n_pos, pos_ce, hard, l1_sum, out);
}